// Round 1
// baseline (1311.107 us; speedup 1.0000x reference)
//
#include <hip/hip_runtime.h>
#include <stdint.h>

#define HW 4096
#define CH 384
#define NB 8
#define K_SEL 128
#define BIG_DIST 1.0e7f
#define BIG_DIFF 10000.0f

typedef unsigned long long u64;

__device__ __forceinline__ u64 encode_di(float d, int idx) {
    // d >= 0 always (sqrt result or 1e7/1e4 fill), so float bits are monotone.
    return ((u64)__float_as_uint(d) << 32) | (unsigned)idx;
}

// ---------------------------------------------------------------- init slots
__global__ void init_slots(u64* s, int n) {
    int i = blockIdx.x * blockDim.x + threadIdx.x;
    if (i < n) s[i] = ~0ULL;
}

// ------------------------------------------------------- row norms + sq sums
// one wave (64 lanes) per row; 2*NB*HW rows total
__global__ void normalize_rows(const float* __restrict__ f1,
                               const float* __restrict__ f2,
                               const int* __restrict__ mask1,
                               const int* __restrict__ mask2,
                               float* __restrict__ rn1, float* __restrict__ rn2,
                               float* __restrict__ sq1, float* __restrict__ sq2) {
    int gw = (blockIdx.x * blockDim.x + threadIdx.x) >> 6;
    int lane = threadIdx.x & 63;
    int which = gw >> 15;          // 32768 rows per tensor
    int row = gw & 32767;          // b*HW + i
    const float* f = which ? f2 : f1;
    const int* m = which ? mask2 : mask1;
    float* rn = which ? rn2 : rn1;
    float* sq = which ? sq2 : sq1;

    const float* p = f + (size_t)row * CH;
    float x[6];
    float s = 0.f;
#pragma unroll
    for (int t = 0; t < 6; ++t) { x[t] = p[lane + 64 * t]; s += x[t] * x[t]; }
#pragma unroll
    for (int off = 32; off >= 1; off >>= 1) s += __shfl_xor(s, off, 64);
    float r = 1.0f / __fsqrt_rn(s);
    float s2 = 0.f;
#pragma unroll
    for (int t = 0; t < 6; ++t) { float y = x[t] * r; s2 += y * y; }
#pragma unroll
    for (int off = 32; off >= 1; off >>= 1) s2 += __shfl_xor(s2, off, 64);
    if (lane == 0) {
        rn[row] = r;
        sq[row] = (m[row] > 0) ? s2 : 0.0f;
    }
}

// ----------------------------------------------- fused GEMM + row/col argmin
#define BM 128
#define BN 128
#define BK 32
#define LSTR 132   // padded LDS row stride (floats); keeps b128 reads 16B-aligned

__global__ __launch_bounds__(256)
void gemm_argmin(const float* __restrict__ f1, const float* __restrict__ f2,
                 const int* __restrict__ mask1, const int* __restrict__ mask2,
                 const float* __restrict__ rn1, const float* __restrict__ rn2,
                 const float* __restrict__ sq1, const float* __restrict__ sq2,
                 u64* __restrict__ slot1, u64* __restrict__ slot2) {
    __shared__ float As[BK][LSTR];
    __shared__ float Bs[BK][LSTR];
    __shared__ u64 rowSlot[BM];
    __shared__ u64 colSlot[BN];

    const int b = blockIdx.z;
    const int brow = blockIdx.y * BM;
    const int bcol = blockIdx.x * BN;
    const int tid = threadIdx.x;
    const int tx = tid & 15, ty = tid >> 4;

    const float* A = f1 + (size_t)b * HW * CH;
    const float* B = f2 + (size_t)b * HW * CH;

    const int k4 = tid & 7;     // which 4-float chunk of the 32 k-columns
    const int mrow = tid >> 3;  // 0..31

    // per-thread staging row scales (rows mrow, mrow+32, mrow+64, mrow+96)
    float ra[4], rb[4];
#pragma unroll
    for (int p = 0; p < 4; ++p) {
        ra[p] = rn1[b * HW + brow + mrow + 32 * p];
        rb[p] = rn2[b * HW + bcol + mrow + 32 * p];
    }

    float acc[8][8] = {};

    for (int kb = 0; kb < CH; kb += BK) {
#pragma unroll
        for (int p = 0; p < 4; ++p) {
            int row = mrow + 32 * p;
            float4 ga = *(const float4*)(A + (size_t)(brow + row) * CH + kb + k4 * 4);
            As[k4 * 4 + 0][row] = ga.x * ra[p];
            As[k4 * 4 + 1][row] = ga.y * ra[p];
            As[k4 * 4 + 2][row] = ga.z * ra[p];
            As[k4 * 4 + 3][row] = ga.w * ra[p];
            float4 gb = *(const float4*)(B + (size_t)(bcol + row) * CH + kb + k4 * 4);
            Bs[k4 * 4 + 0][row] = gb.x * rb[p];
            Bs[k4 * 4 + 1][row] = gb.y * rb[p];
            Bs[k4 * 4 + 2][row] = gb.z * rb[p];
            Bs[k4 * 4 + 3][row] = gb.w * rb[p];
        }
        __syncthreads();
#pragma unroll
        for (int kk = 0; kk < BK; ++kk) {
            float4 a0 = *(const float4*)&As[kk][ty * 8];
            float4 a1 = *(const float4*)&As[kk][ty * 8 + 4];
            float4 b0 = *(const float4*)&Bs[kk][tx * 8];
            float4 b1 = *(const float4*)&Bs[kk][tx * 8 + 4];
            float av[8] = {a0.x, a0.y, a0.z, a0.w, a1.x, a1.y, a1.z, a1.w};
            float bv[8] = {b0.x, b0.y, b0.z, b0.w, b1.x, b1.y, b1.z, b1.w};
#pragma unroll
            for (int r = 0; r < 8; ++r)
#pragma unroll
                for (int s = 0; s < 8; ++s)
                    acc[r][s] += av[r] * bv[s];
        }
        __syncthreads();
    }

    // -------- epilogue: d = valid ? sqrt(max(sq1+sq2-2dot,0)) : 1e7, argmins
    if (tid < BM) { rowSlot[tid] = ~0ULL; colSlot[tid] = ~0ULL; }
    __syncthreads();

    const int i_base = brow + ty * 8;
    const int j_base = bcol + tx * 8;
    float s1v[8], s2v[8];
    int m1v[8], m2v[8];
#pragma unroll
    for (int r = 0; r < 8; ++r) {
        s1v[r] = sq1[b * HW + i_base + r];
        m1v[r] = mask1[b * HW + i_base + r];
    }
#pragma unroll
    for (int s = 0; s < 8; ++s) {
        s2v[s] = sq2[b * HW + j_base + s];
        m2v[s] = mask2[b * HW + j_base + s];
    }

    u64 rbest[8], cbest[8];
#pragma unroll
    for (int r = 0; r < 8; ++r) rbest[r] = ~0ULL;
#pragma unroll
    for (int s = 0; s < 8; ++s) cbest[s] = ~0ULL;

#pragma unroll
    for (int r = 0; r < 8; ++r) {
#pragma unroll
        for (int s = 0; s < 8; ++s) {
            float d;
            if (m1v[r] && m2v[s]) {
                // ((sq1 + sq2) - 2*dot) with controlled rounding (no contraction)
                float t = __fmul_rn(2.0f, acc[r][s]);
                float d2 = __fsub_rn(__fadd_rn(s1v[r], s2v[s]), t);
                d = __fsqrt_rn(fmaxf(d2, 0.0f));
            } else {
                d = BIG_DIST;
            }
            u64 er = encode_di(d, j_base + s);
            u64 ec = encode_di(d, i_base + r);
            if (er < rbest[r]) rbest[r] = er;
            if (ec < cbest[s]) cbest[s] = ec;
        }
    }
#pragma unroll
    for (int r = 0; r < 8; ++r) atomicMin(&rowSlot[ty * 8 + r], rbest[r]);
#pragma unroll
    for (int s = 0; s < 8; ++s) atomicMin(&colSlot[tx * 8 + s], cbest[s]);
    __syncthreads();

    if (tid < BM) atomicMin(&slot1[(size_t)b * HW + brow + tid], rowSlot[tid]);
    if (tid < BN) atomicMin(&slot2[(size_t)b * HW + bcol + tid], colSlot[tid]);
}

// ------------------------------------------------------------ extract matches
__global__ void extract_matches(const u64* __restrict__ slot1,
                                const u64* __restrict__ slot2,
                                int* __restrict__ match1, int* __restrict__ match2,
                                int n) {
    int i = blockIdx.x * blockDim.x + threadIdx.x;
    if (i < n) {
        match1[i] = (int)(unsigned)(slot1[i] & 0xFFFFFFFFu);
        match2[i] = (int)(unsigned)(slot2[i] & 0xFFFFFFFFu);
    }
}

// -------------------------------------------------------- cyclic coord keys
__global__ void compute_keys(const int* __restrict__ match1,
                             const int* __restrict__ match2,
                             const int* __restrict__ mask1,
                             const int* __restrict__ mask2,
                             u64* __restrict__ key1, u64* __restrict__ key2) {
    int g = blockIdx.x * blockDim.x + threadIdx.x;
    if (g >= NB * HW) return;
    int i = g & (HW - 1);
    int base = g - i;
    float gx = (float)(i >> 6), gy = (float)(i & 63);
    // dir 1: fwd=match1, bwd=match2, src mask m1, dst mask m2
    {
        int mf = match1[g];
        int dst_valid = mask2[base + mf];
        int cyc = match2[base + mf];
        float dx = (float)(cyc >> 6) - gx;
        float dy = (float)(cyc & 63) - gy;
        float diff = __fsqrt_rn(dx * dx + dy * dy);
        float v = ((mask1[g] > 0) && (dst_valid > 0)) ? diff : BIG_DIFF;
        key1[g] = encode_di(v, i);
    }
    // dir 2: fwd=match2, bwd=match1, src mask m2, dst mask m1
    {
        int mf = match2[g];
        int dst_valid = mask1[base + mf];
        int cyc = match1[base + mf];
        float dx = (float)(cyc >> 6) - gx;
        float dy = (float)(cyc & 63) - gy;
        float diff = __fsqrt_rn(dx * dx + dy * dy);
        float v = ((mask2[g] > 0) && (dst_valid > 0)) ? diff : BIG_DIFF;
        key2[g] = encode_di(v, i);
    }
}

// ----------------------------------------------- top-K via LDS bitonic sort
__global__ __launch_bounds__(1024)
void topk_output(const u64* __restrict__ key1, const u64* __restrict__ key2,
                 const int* __restrict__ match1, const int* __restrict__ match2,
                 const int* __restrict__ mask1, const int* __restrict__ mask2,
                 const int* __restrict__ backup1, const int* __restrict__ backup2,
                 int* __restrict__ out) {
    __shared__ u64 keys[HW];
    __shared__ int cnt;
    const int b = blockIdx.x;
    const int dir = blockIdx.y;
    const u64* key = dir ? key2 : key1;
    const int* match = dir ? match2 : match1;
    const int* mask = dir ? mask2 : mask1;
    const int* backup = dir ? backup2 : backup1;
    const int tid = threadIdx.x;
    const size_t base = (size_t)b * HW;

    if (tid == 0) cnt = 0;
    __syncthreads();
    int local = 0;
    for (int t = tid; t < HW; t += 1024) {
        keys[t] = key[base + t];
        local += (mask[base + t] > 0) ? 1 : 0;
    }
    atomicAdd(&cnt, local);
    __syncthreads();

    for (unsigned k = 2; k <= HW; k <<= 1) {
        for (unsigned j = k >> 1; j > 0; j >>= 1) {
            for (unsigned t = tid; t < HW; t += 1024) {
                unsigned ixj = t ^ j;
                if (ixj > t) {
                    u64 a = keys[t], c = keys[ixj];
                    bool up = ((t & k) == 0);
                    if ((a > c) == up) { keys[t] = c; keys[ixj] = a; }
                }
            }
            __syncthreads();
        }
    }

    if (tid < K_SEL) {
        int c;
        if (cnt >= K_SEL) c = (int)(unsigned)(keys[tid] & 0xFFFFFFFFu);
        else c = backup[b * K_SEL + tid];
        int cm = match[base + c];
        int* o = out + dir * (NB * K_SEL * 2);
        o[(b * K_SEL + tid) * 2 + 0] = c;
        o[(b * K_SEL + tid) * 2 + 1] = cm;
    }
}

// ---------------------------------------------------------------------------
extern "C" void kernel_launch(void* const* d_in, const int* in_sizes, int n_in,
                              void* d_out, int out_size, void* d_ws, size_t ws_size,
                              hipStream_t stream) {
    const float* f1 = (const float*)d_in[0];
    const float* f2 = (const float*)d_in[1];
    const int* mask1 = (const int*)d_in[2];
    const int* mask2 = (const int*)d_in[3];
    const int* backup1 = (const int*)d_in[4];
    const int* backup2 = (const int*)d_in[5];
    int* out = (int*)d_out;

    char* ws = (char*)d_ws;
    u64* slot1 = (u64*)ws;            ws += (size_t)NB * HW * 8;
    u64* slot2 = (u64*)ws;            ws += (size_t)NB * HW * 8;
    u64* key1  = (u64*)ws;            ws += (size_t)NB * HW * 8;
    u64* key2  = (u64*)ws;            ws += (size_t)NB * HW * 8;
    float* rn1 = (float*)ws;          ws += (size_t)NB * HW * 4;
    float* rn2 = (float*)ws;          ws += (size_t)NB * HW * 4;
    float* sq1 = (float*)ws;          ws += (size_t)NB * HW * 4;
    float* sq2 = (float*)ws;          ws += (size_t)NB * HW * 4;
    int* match1 = (int*)ws;           ws += (size_t)NB * HW * 4;
    int* match2 = (int*)ws;           ws += (size_t)NB * HW * 4;

    const int nrows = NB * HW;

    init_slots<<<(2 * nrows + 255) / 256, 256, 0, stream>>>(slot1, 2 * nrows);
    normalize_rows<<<(2 * nrows) / 4, 256, 0, stream>>>(f1, f2, mask1, mask2,
                                                        rn1, rn2, sq1, sq2);
    dim3 g(HW / BN, HW / BM, NB);
    gemm_argmin<<<g, 256, 0, stream>>>(f1, f2, mask1, mask2, rn1, rn2,
                                       sq1, sq2, slot1, slot2);
    extract_matches<<<(nrows + 255) / 256, 256, 0, stream>>>(slot1, slot2,
                                                             match1, match2, nrows);
    compute_keys<<<(nrows + 255) / 256, 256, 0, stream>>>(match1, match2,
                                                          mask1, mask2, key1, key2);
    topk_output<<<dim3(NB, 2), 1024, 0, stream>>>(key1, key2, match1, match2,
                                                  mask1, mask2, backup1, backup2,
                                                  out);
}

// Round 2
// 472.014 us; speedup vs baseline: 2.7777x; 2.7777x over previous
//
#include <hip/hip_runtime.h>
#include <stdint.h>

#define HW 4096
#define CH 384
#define NB 8
#define K_SEL 128
#define BIG_DIST 1.0e7f
#define BIG_DIFF 10000.0f
#define PAGE 8192          // one 128x32 f16 tile = 8 KB
#define NKB 12             // 384 / 32
#define NRB 32             // 4096 / 128

typedef unsigned long long u64;
typedef _Float16 f16;
typedef _Float16 f16x8 __attribute__((ext_vector_type(8)));
typedef float f32x4 __attribute__((ext_vector_type(4)));

__device__ __forceinline__ u64 encode_di(float d, int idx) {
    // d >= 0 always, so float bits are order-isomorphic.
    return ((u64)__float_as_uint(d) << 32) | (unsigned)idx;
}

__device__ __forceinline__ void gl_lds16(const void* g, void* l) {
    __builtin_amdgcn_global_load_lds(
        (const __attribute__((address_space(1))) unsigned int*)g,
        (__attribute__((address_space(3))) unsigned int*)l, 16, 0, 0);
}

// XOR swizzle of a byte offset inside one 128x32 f16 page: spreads the
// 64B rows across banks so ds_read_b128 column-slices are ~conflict-free.
__device__ __forceinline__ int swz(int row, int bytecol) {
    return (row * 64 + bytecol) ^ ((row & 7) << 4);
}

// ---------------------------------------------------------------- init slots
__global__ void init_slots(u64* s, int n) {
    int i = blockIdx.x * blockDim.x + threadIdx.x;
    if (i < n) s[i] = ~0ULL;
}

// ------------------------------------------------------- row norms + sq sums
__global__ void normalize_rows(const float* __restrict__ f1,
                               const float* __restrict__ f2,
                               const int* __restrict__ mask1,
                               const int* __restrict__ mask2,
                               float* __restrict__ rn1, float* __restrict__ rn2,
                               float* __restrict__ sq1, float* __restrict__ sq2) {
    int gw = (blockIdx.x * blockDim.x + threadIdx.x) >> 6;
    int lane = threadIdx.x & 63;
    int which = gw >> 15;
    int row = gw & 32767;
    const float* f = which ? f2 : f1;
    const int* m = which ? mask2 : mask1;
    float* rn = which ? rn2 : rn1;
    float* sq = which ? sq2 : sq1;

    const float* p = f + (size_t)row * CH;
    float x[6];
    float s = 0.f;
#pragma unroll
    for (int t = 0; t < 6; ++t) { x[t] = p[lane + 64 * t]; s += x[t] * x[t]; }
#pragma unroll
    for (int off = 32; off >= 1; off >>= 1) s += __shfl_xor(s, off, 64);
    float r = 1.0f / __fsqrt_rn(s);
    float s2 = 0.f;
#pragma unroll
    for (int t = 0; t < 6; ++t) { float y = x[t] * r; s2 += y * y; }
#pragma unroll
    for (int off = 32; off >= 1; off >>= 1) s2 += __shfl_xor(s2, off, 64);
    if (lane == 0) {
        rn[row] = r;
        sq[row] = (m[row] > 0) ? s2 : 0.0f;
    }
}

// ----------------------------- split f32 -> (hi f16, lo f16 * 2048), pre-tiled
// page layout: tensor[((b*NRB+rb)*NKB+kb)*2 + {0=hi,1=lo}] of 8KB, element
// (r,k) at swizzled byte (r*64 + k*2) ^ ((r&7)<<4).
__global__ __launch_bounds__(256)
void convert_tiles(const float* __restrict__ f1, const float* __restrict__ f2,
                   const float* __restrict__ rn1, const float* __restrict__ rn2,
                   char* __restrict__ tA, char* __restrict__ tB) {
    int lin = blockIdx.x;                 // (b*NRB+rb)*NKB + kb
    int kb = lin % NKB;
    int rb = (lin / NKB) % NRB;
    int b = lin / (NKB * NRB);
    const float* f = blockIdx.y ? f2 : f1;
    const float* rn = blockIdx.y ? rn2 : rn1;
    char* t = blockIdx.y ? tB : tA;
    char* hipg = t + (size_t)lin * 2 * PAGE;
    char* lopg = hipg + PAGE;
    int rowbase = rb * 128;

#pragma unroll
    for (int p = 0; p < 4; ++p) {
        int q = p * 256 + threadIdx.x;    // 0..1023
        int r = q >> 3;                   // local row 0..127
        int kq = q & 7;                   // which float4 of the 32 k
        int grow = rowbase + r;
        float rv = rn[b * HW + grow];
        float4 x = *(const float4*)(f + ((size_t)b * HW + grow) * CH + kb * 32 + kq * 4);
        x.x *= rv; x.y *= rv; x.z *= rv; x.w *= rv;
        f16 h0 = (f16)x.x, h1 = (f16)x.y, h2 = (f16)x.z, h3 = (f16)x.w;
        f16 l0 = (f16)((x.x - (float)h0) * 2048.0f);
        f16 l1 = (f16)((x.y - (float)h1) * 2048.0f);
        f16 l2 = (f16)((x.z - (float)h2) * 2048.0f);
        f16 l3 = (f16)((x.w - (float)h3) * 2048.0f);
        int off = swz(r, kq * 8);
        union { f16 h[4]; uint2 u; } H = {{h0, h1, h2, h3}};
        union { f16 h[4]; uint2 u; } L = {{l0, l1, l2, l3}};
        *(uint2*)(hipg + off) = H.u;
        *(uint2*)(lopg + off) = L.u;
    }
}

// ----------------------------------------- fused split-MFMA GEMM + argmin
__global__ __launch_bounds__(256, 2)
void gemm_argmin(const char* __restrict__ tA, const char* __restrict__ tB,
                 const int* __restrict__ mask1, const int* __restrict__ mask2,
                 const float* __restrict__ sq1, const float* __restrict__ sq2,
                 u64* __restrict__ slot1, u64* __restrict__ slot2) {
    __shared__ __align__(16) char smem[4 * PAGE];   // Ahi Alo Bhi Blo
    __shared__ u64 rowSlot[128];
    __shared__ u64 colSlot[128];

    const int b = blockIdx.y;
    const int tid = threadIdx.x;

    // XCD-aware swizzle: each XCD owns a 32(by) x 4(bx) panel of the 32x32 grid
    int orig = blockIdx.x;                // 0..1023
    int xcd = orig & 7;
    int i5 = orig >> 3;                   // 0..127
    int bx = xcd * 4 + (i5 & 3);
    int by = i5 >> 2;
    const int brow = by * 128, bcol = bx * 128;

    const char* Abase = tA + (size_t)(b * NRB + by) * NKB * 2 * PAGE;
    const char* Bbase = tB + (size_t)(b * NRB + bx) * NKB * 2 * PAGE;

    const int wv = tid >> 6, lane = tid & 63;
    const int wr = wv >> 1, wc = wv & 1;   // wave grid 2x2, wave tile 64x64
    const int r0 = lane & 15, kc = lane >> 4;

    int aoff[4], boff[4];
#pragma unroll
    for (int m = 0; m < 4; ++m) {
        int ra = wr * 64 + m * 16 + r0;
        aoff[m] = swz(ra, kc * 16);
        int rb_ = wc * 64 + m * 16 + r0;
        boff[m] = swz(rb_, kc * 16);
    }

    f32x4 acc[4][4], acc2[4][4];
    f32x4 zero = {0.f, 0.f, 0.f, 0.f};
#pragma unroll
    for (int m = 0; m < 4; ++m)
#pragma unroll
        for (int n = 0; n < 4; ++n) { acc[m][n] = zero; acc2[m][n] = zero; }

    const int stg = wv * 1024;            // wave-uniform LDS chunk base
    const int src_l = stg + lane * 16;

    for (int kb = 0; kb < NKB; ++kb) {
        const char* gA = Abase + (size_t)kb * 2 * PAGE;
        const char* gB = Bbase + (size_t)kb * 2 * PAGE;
#pragma unroll
        for (int p = 0; p < 4; ++p) {
            gl_lds16(gA + p * 4096 + src_l, smem + p * 4096 + stg);
            gl_lds16(gB + p * 4096 + src_l, smem + 16384 + p * 4096 + stg);
        }
        asm volatile("s_waitcnt vmcnt(0)" ::: "memory");
        __syncthreads();

        f16x8 bh[4], bl[4];
#pragma unroll
        for (int n = 0; n < 4; ++n) {
            bh[n] = *(const f16x8*)(smem + 2 * PAGE + boff[n]);
            bl[n] = *(const f16x8*)(smem + 3 * PAGE + boff[n]);
        }
#pragma unroll
        for (int m = 0; m < 4; ++m) {
            f16x8 ah = *(const f16x8*)(smem + aoff[m]);
            f16x8 al = *(const f16x8*)(smem + PAGE + aoff[m]);
#pragma unroll
            for (int n = 0; n < 4; ++n) {
                acc[m][n]  = __builtin_amdgcn_mfma_f32_16x16x32_f16(ah, bh[n], acc[m][n], 0, 0, 0);
                acc2[m][n] = __builtin_amdgcn_mfma_f32_16x16x32_f16(ah, bl[n], acc2[m][n], 0, 0, 0);
                acc2[m][n] = __builtin_amdgcn_mfma_f32_16x16x32_f16(al, bh[n], acc2[m][n], 0, 0, 0);
            }
        }
        __syncthreads();
    }

    // ---------------- epilogue: d + row/col argmin (u64-encoded)
    if (tid < 128) { rowSlot[tid] = ~0ULL; colSlot[tid] = ~0ULL; }
    __syncthreads();

    const size_t bb = (size_t)b * HW;
    const int rfrag = (lane >> 4) * 4;     // C/D: row = (lane>>4)*4 + reg, col = lane&15
    float s1v[4][4];
    int m1v[4][4];
#pragma unroll
    for (int m = 0; m < 4; ++m) {
        int rr = brow + wr * 64 + m * 16 + rfrag;
        float4 s = *(const float4*)(sq1 + bb + rr);
        int4 mm = *(const int4*)(mask1 + bb + rr);
        s1v[m][0] = s.x; s1v[m][1] = s.y; s1v[m][2] = s.z; s1v[m][3] = s.w;
        m1v[m][0] = mm.x; m1v[m][1] = mm.y; m1v[m][2] = mm.z; m1v[m][3] = mm.w;
    }
    float s2v[4];
    int m2v[4];
#pragma unroll
    for (int n = 0; n < 4; ++n) {
        int cc = bcol + wc * 64 + n * 16 + r0;
        s2v[n] = sq2[bb + cc];
        m2v[n] = mask2[bb + cc];
    }

    u64 cbest[4] = {~0ULL, ~0ULL, ~0ULL, ~0ULL};
#pragma unroll
    for (int m = 0; m < 4; ++m) {
#pragma unroll
        for (int j = 0; j < 4; ++j) {
            u64 rbest = ~0ULL;
            int rr = brow + wr * 64 + m * 16 + rfrag + j;
#pragma unroll
            for (int n = 0; n < 4; ++n) {
                float dot = acc[m][n][j] + acc2[m][n][j] * (1.0f / 2048.0f);
                float d;
                if (m1v[m][j] && m2v[n]) {
                    float t = __fmul_rn(2.0f, dot);
                    float d2 = __fsub_rn(__fadd_rn(s1v[m][j], s2v[n]), t);
                    d = __fsqrt_rn(fmaxf(d2, 0.0f));
                } else {
                    d = BIG_DIST;
                }
                int cc = bcol + wc * 64 + n * 16 + r0;
                u64 er = encode_di(d, cc);
                u64 ec = encode_di(d, rr);
                if (er < rbest) rbest = er;
                if (ec < cbest[n]) cbest[n] = ec;
            }
            atomicMin(&rowSlot[wr * 64 + m * 16 + rfrag + j], rbest);
        }
    }
#pragma unroll
    for (int n = 0; n < 4; ++n)
        atomicMin(&colSlot[wc * 64 + n * 16 + r0], cbest[n]);
    __syncthreads();

    if (tid < 128) atomicMin(&slot1[bb + brow + tid], rowSlot[tid]);
    else           atomicMin(&slot2[bb + bcol + tid - 128], colSlot[tid - 128]);
}

// ------------------------------------------------------------ extract matches
__global__ void extract_matches(const u64* __restrict__ slot1,
                                const u64* __restrict__ slot2,
                                int* __restrict__ match1, int* __restrict__ match2,
                                int n) {
    int i = blockIdx.x * blockDim.x + threadIdx.x;
    if (i < n) {
        match1[i] = (int)(unsigned)(slot1[i] & 0xFFFFFFFFu);
        match2[i] = (int)(unsigned)(slot2[i] & 0xFFFFFFFFu);
    }
}

// -------------------------------------------------------- cyclic coord keys
__global__ void compute_keys(const int* __restrict__ match1,
                             const int* __restrict__ match2,
                             const int* __restrict__ mask1,
                             const int* __restrict__ mask2,
                             u64* __restrict__ key1, u64* __restrict__ key2) {
    int g = blockIdx.x * blockDim.x + threadIdx.x;
    if (g >= NB * HW) return;
    int i = g & (HW - 1);
    int base = g - i;
    float gx = (float)(i >> 6), gy = (float)(i & 63);
    {
        int mf = match1[g];
        int dst_valid = mask2[base + mf];
        int cyc = match2[base + mf];
        float dx = (float)(cyc >> 6) - gx;
        float dy = (float)(cyc & 63) - gy;
        float diff = __fsqrt_rn(dx * dx + dy * dy);
        float v = ((mask1[g] > 0) && (dst_valid > 0)) ? diff : BIG_DIFF;
        key1[g] = encode_di(v, i);
    }
    {
        int mf = match2[g];
        int dst_valid = mask1[base + mf];
        int cyc = match1[base + mf];
        float dx = (float)(cyc >> 6) - gx;
        float dy = (float)(cyc & 63) - gy;
        float diff = __fsqrt_rn(dx * dx + dy * dy);
        float v = ((mask2[g] > 0) && (dst_valid > 0)) ? diff : BIG_DIFF;
        key2[g] = encode_di(v, i);
    }
}

// ----------------------------------------------- top-K via LDS bitonic sort
__global__ __launch_bounds__(1024)
void topk_output(const u64* __restrict__ key1, const u64* __restrict__ key2,
                 const int* __restrict__ match1, const int* __restrict__ match2,
                 const int* __restrict__ mask1, const int* __restrict__ mask2,
                 const int* __restrict__ backup1, const int* __restrict__ backup2,
                 int* __restrict__ out) {
    __shared__ u64 keys[HW];
    __shared__ int cnt;
    const int b = blockIdx.x;
    const int dir = blockIdx.y;
    const u64* key = dir ? key2 : key1;
    const int* match = dir ? match2 : match1;
    const int* mask = dir ? mask2 : mask1;
    const int* backup = dir ? backup2 : backup1;
    const int tid = threadIdx.x;
    const size_t base = (size_t)b * HW;

    if (tid == 0) cnt = 0;
    __syncthreads();
    int local = 0;
    for (int t = tid; t < HW; t += 1024) {
        keys[t] = key[base + t];
        local += (mask[base + t] > 0) ? 1 : 0;
    }
    atomicAdd(&cnt, local);
    __syncthreads();

    for (unsigned k = 2; k <= HW; k <<= 1) {
        for (unsigned j = k >> 1; j > 0; j >>= 1) {
            for (unsigned t = tid; t < HW; t += 1024) {
                unsigned ixj = t ^ j;
                if (ixj > t) {
                    u64 a = keys[t], c = keys[ixj];
                    bool up = ((t & k) == 0);
                    if ((a > c) == up) { keys[t] = c; keys[ixj] = a; }
                }
            }
            __syncthreads();
        }
    }

    if (tid < K_SEL) {
        int c;
        if (cnt >= K_SEL) c = (int)(unsigned)(keys[tid] & 0xFFFFFFFFu);
        else c = backup[b * K_SEL + tid];
        int cm = match[base + c];
        int* o = out + dir * (NB * K_SEL * 2);
        o[(b * K_SEL + tid) * 2 + 0] = c;
        o[(b * K_SEL + tid) * 2 + 1] = cm;
    }
}

// ---------------------------------------------------------------------------
extern "C" void kernel_launch(void* const* d_in, const int* in_sizes, int n_in,
                              void* d_out, int out_size, void* d_ws, size_t ws_size,
                              hipStream_t stream) {
    const float* f1 = (const float*)d_in[0];
    const float* f2 = (const float*)d_in[1];
    const int* mask1 = (const int*)d_in[2];
    const int* mask2 = (const int*)d_in[3];
    const int* backup1 = (const int*)d_in[4];
    const int* backup2 = (const int*)d_in[5];
    int* out = (int*)d_out;

    char* ws = (char*)d_ws;
    char* tA = ws;                    ws += (size_t)NB * NRB * NKB * 2 * PAGE;
    char* tB = ws;                    ws += (size_t)NB * NRB * NKB * 2 * PAGE;
    u64* slot1 = (u64*)ws;            ws += (size_t)NB * HW * 8;
    u64* slot2 = (u64*)ws;            ws += (size_t)NB * HW * 8;
    u64* key1 = (u64*)ws;             ws += (size_t)NB * HW * 8;
    u64* key2 = (u64*)ws;             ws += (size_t)NB * HW * 8;
    float* rn1 = (float*)ws;          ws += (size_t)NB * HW * 4;
    float* rn2 = (float*)ws;          ws += (size_t)NB * HW * 4;
    float* sq1 = (float*)ws;          ws += (size_t)NB * HW * 4;
    float* sq2 = (float*)ws;          ws += (size_t)NB * HW * 4;
    int* match1 = (int*)ws;           ws += (size_t)NB * HW * 4;
    int* match2 = (int*)ws;           ws += (size_t)NB * HW * 4;

    const int nrows = NB * HW;

    init_slots<<<(2 * nrows + 255) / 256, 256, 0, stream>>>(slot1, 2 * nrows);
    normalize_rows<<<(2 * nrows) / 4, 256, 0, stream>>>(f1, f2, mask1, mask2,
                                                        rn1, rn2, sq1, sq2);
    convert_tiles<<<dim3(NB * NRB * NKB, 2), 256, 0, stream>>>(f1, f2, rn1, rn2, tA, tB);
    gemm_argmin<<<dim3(1024, NB), 256, 0, stream>>>(tA, tB, mask1, mask2,
                                                    sq1, sq2, slot1, slot2);
    extract_matches<<<(nrows + 255) / 256, 256, 0, stream>>>(slot1, slot2,
                                                             match1, match2, nrows);
    compute_keys<<<(nrows + 255) / 256, 256, 0, stream>>>(match1, match2,
                                                          mask1, mask2, key1, key2);
    topk_output<<<dim3(NB, 2), 1024, 0, stream>>>(key1, key2, match1, match2,
                                                  mask1, mask2, backup1, backup2,
                                                  out);
}